// Round 5
// baseline (1990.725 us; speedup 1.0000x reference)
//
#include <hip/hip_runtime.h>

typedef unsigned short u16;
typedef unsigned int u32;
typedef __attribute__((ext_vector_type(8))) short bf16x8;
typedef __attribute__((ext_vector_type(4))) float f32x4;
typedef __attribute__((ext_vector_type(16))) float f32x16;
typedef __attribute__((ext_vector_type(4))) u16 u16x4;
typedef __attribute__((ext_vector_type(4))) u32 u32x4;

__device__ __forceinline__ u16 f2bf(float f) {
  u32 u = __builtin_bit_cast(u32, f);
  return (u16)((u + 0x7FFFu + ((u >> 16) & 1u)) >> 16);
}

__device__ __forceinline__ f32x4 mfma16(bf16x8 a, bf16x8 b, f32x4 c) {
  return __builtin_amdgcn_mfma_f32_16x16x32_bf16(a, b, c, 0, 0, 0);
}
__device__ __forceinline__ f32x16 mfma32(bf16x8 a, bf16x8 b, f32x16 c) {
  return __builtin_amdgcn_mfma_f32_32x32x16_bf16(a, b, c, 0, 0, 0);
}

__device__ __forceinline__ void gload16(const void* g, void* l) {
  __builtin_amdgcn_global_load_lds(
      (const __attribute__((address_space(1))) unsigned int*)g,
      (__attribute__((address_space(3))) unsigned int*)l, 16, 0, 0);
}

__device__ __forceinline__ u32 cvtpk(float lo, float hi) {
  u32 r;
  asm volatile("v_cvt_pk_bf16_f32 %0, %1, %2" : "=v"(r) : "v"(lo), "v"(hi));
  return r;
}
__device__ __forceinline__ void pl32swap(u32& a, u32& b) {
  asm volatile("v_permlane32_swap_b32 %0, %1" : "+v"(a), "+v"(b));
}

// ---------------- pack kernels ----------------

__global__ void pack_x_kernel(const float* __restrict__ x, u16* __restrict__ xb) {
  const int i = blockIdx.x * 256 + threadIdx.x;
  const float4 v = ((const float4*)x)[i];
  u16x4 o;
  o[0] = f2bf(v.x); o[1] = f2bf(v.y); o[2] = f2bf(v.z); o[3] = f2bf(v.w);
  ((u16x4*)xb)[i] = o;
}

// W: [512][4096] col = k*8+h  ->  Wp: [h*512+k][dd]  (tiled LDS transpose)
__global__ void pack_wqkv_t(const float* __restrict__ W, u16* __restrict__ Wp) {
  __shared__ u16 tile[64][72];
  const int t = threadIdx.x;
  const int c0 = blockIdx.x * 64, dd0 = blockIdx.y * 64;
#pragma unroll
  for (int s = 0; s < 4; ++s) {
    const int r = s * 16 + (t >> 4);
    const int q = (t & 15) * 4;
    const float4 v = *(const float4*)&W[(size_t)(dd0 + r) * 4096 + c0 + q];
    tile[r][q + 0] = f2bf(v.x); tile[r][q + 1] = f2bf(v.y);
    tile[r][q + 2] = f2bf(v.z); tile[r][q + 3] = f2bf(v.w);
  }
  __syncthreads();
#pragma unroll
  for (int s = 0; s < 4; ++s) {
    const int cl = s * 16 + (t >> 4);
    const int u = t & 15;
    const int cg = c0 + cl;
    const int orow = (cg & 7) * 512 + (cg >> 3);
    u16x4 o;
#pragma unroll
    for (int i = 0; i < 4; ++i) o[i] = tile[u * 4 + i][cl];
    *(u16x4*)&Wp[(size_t)orow * 512 + dd0 + u * 4] = o;
  }
}

// Wo: [4096][512] -> Wot: [n=512][k=4096]
__global__ void pack_wo_t(const float* __restrict__ W, u16* __restrict__ Wp) {
  __shared__ u16 tile[64][72];
  const int t = threadIdx.x;
  const int k0 = blockIdx.x * 64, n0 = blockIdx.y * 64;
#pragma unroll
  for (int s = 0; s < 4; ++s) {
    const int r = s * 16 + (t >> 4);
    const int q = (t & 15) * 4;
    const float4 v = *(const float4*)&W[(size_t)(k0 + r) * 512 + n0 + q];
    tile[r][q + 0] = f2bf(v.x); tile[r][q + 1] = f2bf(v.y);
    tile[r][q + 2] = f2bf(v.z); tile[r][q + 3] = f2bf(v.w);
  }
  __syncthreads();
#pragma unroll
  for (int s = 0; s < 4; ++s) {
    const int cl = s * 16 + (t >> 4);
    const int u = t & 15;
    u16x4 o;
#pragma unroll
    for (int i = 0; i < 4; ++i) o[i] = tile[u * 4 + i][cl];
    *(u16x4*)&Wp[(size_t)(n0 + cl) * 4096 + k0 + u * 4] = o;
  }
}

// ---------------- GEMM: C[M][N] = A[M][Kd] * B[N][Kd]^T ----------------

template <int MODE>
__global__ __launch_bounds__(256, 2) void gemm_bf16(
    const u16* __restrict__ A, const u16* __restrict__ B,
    void* __restrict__ Cout, const float* __restrict__ bias,
    int Kd, float scale) {
  __shared__ u16 Al[128 * 64];
  __shared__ u16 Bl[128 * 64];
  const int tid = threadIdx.x;
  const int lane = tid & 63;
  const int w = tid >> 6, wm = w >> 1, wn = w & 1;
  const int l15 = lane & 15, lg = lane >> 4;
  const int m0 = blockIdx.y * 128, n0 = blockIdx.x * 128;

  f32x4 acc[4][4];
  const f32x4 zero = {0.f, 0.f, 0.f, 0.f};
#pragma unroll
  for (int i = 0; i < 4; ++i)
#pragma unroll
    for (int j = 0; j < 4; ++j) acc[i][j] = zero;

  const int nk = Kd >> 6;
  for (int kt = 0; kt < nk; ++kt) {
    __syncthreads();
    const int k0 = kt << 6;
#pragma unroll
    for (int s = 0; s < 4; ++s) {
      const int chunk = s * 256 + tid;
      const int row = chunk >> 3, c = chunk & 7;
      const int cs = c ^ (row & 7);
      gload16(A + (size_t)(m0 + row) * Kd + k0 + cs * 8, &Al[chunk * 8]);
    }
#pragma unroll
    for (int s = 0; s < 4; ++s) {
      const int chunk = s * 256 + tid;
      const int row = chunk >> 3, c = chunk & 7;
      const int cs = c ^ (row & 7);
      gload16(B + (size_t)(n0 + row) * Kd + k0 + cs * 8, &Bl[chunk * 8]);
    }
    __syncthreads();
#pragma unroll
    for (int kk = 0; kk < 2; ++kk) {
      bf16x8 af[4], bfr[4];
      const int ch = kk * 4 + lg;
#pragma unroll
      for (int i = 0; i < 4; ++i) {
        const int ar = wm * 64 + i * 16 + l15;
        af[i] = *(const bf16x8*)&Al[ar * 64 + ((ch ^ (ar & 7)) * 8)];
        const int br = wn * 64 + i * 16 + l15;
        bfr[i] = *(const bf16x8*)&Bl[br * 64 + ((ch ^ (br & 7)) * 8)];
      }
#pragma unroll
      for (int i = 0; i < 4; ++i)
#pragma unroll
        for (int j = 0; j < 4; ++j)
          acc[i][j] = mfma16(af[i], bfr[j], acc[i][j]);
    }
  }

#pragma unroll
  for (int i = 0; i < 4; ++i) {
    const int gr0 = m0 + wm * 64 + i * 16 + lg * 4;
#pragma unroll
    for (int j = 0; j < 4; ++j) {
      const int gc = n0 + wn * 64 + j * 16 + l15;
      if constexpr (MODE == 0) {
        u16* O = (u16*)Cout;
        const int h = gc >> 9, d = gc & 511;
#pragma unroll
        for (int r = 0; r < 4; ++r) {
          const int grr = gr0 + r;
          const int bb = grr >> 11, t = grr & 2047;
          O[((size_t)((bb * 8 + h) * 2048 + t) << 9) + d] = f2bf(acc[i][j][r] * scale);
        }
      } else if constexpr (MODE == 1) {
        u16* O = (u16*)Cout;
        const int h = gc >> 9, d = gc & 511;
        const int bb = gr0 >> 11, t = gr0 & 2047;
        u16x4 pk;
#pragma unroll
        for (int r = 0; r < 4; ++r) pk[r] = f2bf(acc[i][j][r]);
        *(u16x4*)&O[((size_t)((bb * 8 + h) * 512 + d) << 11) + t] = pk;
      } else {
        float* O = (float*)Cout;
        const float bv = bias[gc];
#pragma unroll
        for (int r = 0; r < 4; ++r)
          O[(size_t)(gr0 + r) * 512 + gc] = acc[i][j][r] + bv;
      }
    }
  }
}

// ---------------- flash attention v4: K dbuf + raw barriers + V direct-global ----------------
// Q,K: [bh][2048][512]; Vt: [bh][512][2048]; Og: [bb*2048+t][h*512+d]
// block = 4 waves = 2 pairs; pair owns 32 q rows; wave k/d-half = 256.
// KV block 32, 64 steps. Sxf: pair-wise F32 exchange of partial-k S^T.
// LDS = 2x32K (K dbuf) + 16K (Sxf) = 81920 B -> 2 blocks/CU.
// Per step: 2 RAW barriers (no vmcnt drain at the Sxf barrier); K stage for t+1
// stays in flight across softmax/PV; V fragments come global->VGPR in quarters.

__global__ __launch_bounds__(256, 2) void attn_kernel(
    const u16* __restrict__ Qg, const u16* __restrict__ Kg,
    const u16* __restrict__ Vtg, u16* __restrict__ Og, int nbh_pxcd) {
  __shared__ u16 K_lds[2][32 * 512];  // [buf][kv][k]  chunk swz: c ^ (kv&31)
  __shared__ float Sxf[4][32][32];    // per-wave partial S^T, f32, slot-swizzled

  const int tid = threadIdx.x;
  const int lane = tid & 63;
  const int w = tid >> 6;
  const int pr = w >> 1, whalf = w & 1;
  const int l31 = lane & 31, hi = lane >> 5;

  // XCD-aware decode
  const int bid = blockIdx.x;
  const int x8 = bid & 7, rest = bid >> 3;
  const int qt = rest & 31;
  const int bh = x8 * nbh_pxcd + (rest >> 5);

  const size_t bh_off = (size_t)bh * 2048 * 512;
  const u16* Qb = Qg + bh_off;
  const u16* Kb = Kg + bh_off;
  const u16* Vb = Vtg + bh_off;

  // Q as B-fragments: lane holds Q[q = l31][k = whalf*256 + c*16 + hi*8 + j]
  const int qrow = qt * 64 + pr * 32 + l31;
  bf16x8 qf[16];
  {
    const u16* qp = Qb + (size_t)qrow * 512 + whalf * 256 + hi * 8;
#pragma unroll
    for (int c = 0; c < 16; ++c) qf[c] = *(const bf16x8*)(qp + c * 16);
  }

  // per-lane V base: row (whalf*256 + l31), elem offset hi*8; blk adds b*32 rows, chunk adds c*16
  const u16* Vlane = Vb + (size_t)(whalf * 256 + l31) * 2048 + hi * 8;

  f32x16 acc[8];
#pragma unroll
  for (int i = 0; i < 8; ++i) acc[i] = {};
  float m = -1e30f, lsum = 0.f;

  // prologue: stage K tile 0 into buf 0
#pragma unroll
  for (int s = 0; s < 8; ++s) {
    const int chunk = s * 256 + tid;
    const int row = chunk >> 6, c = chunk & 63;
    const int cs = c ^ (row & 31);
    gload16(Kb + (size_t)row * 512 + cs * 8, &K_lds[0][chunk * 8]);
  }
  asm volatile("s_waitcnt vmcnt(0)" ::: "memory");
  __builtin_amdgcn_s_barrier();
  __builtin_amdgcn_sched_barrier(0);

  for (int step = 0; step < 64; ++step) {
    const int cur = step & 1;
    const int t0 = step * 32;
    const u16* Vt0 = Vlane + t0;

    // V quarter A (blks 0,1) — issue early, fly under QK^T
    bf16x8 vA[4], vB[4], vC[4], vD[4];
#pragma unroll
    for (int b2 = 0; b2 < 2; ++b2)
#pragma unroll
      for (int c = 0; c < 2; ++c)
        vA[b2 * 2 + c] = *(const bf16x8*)(Vt0 + (size_t)(b2 * 32) * 2048 + c * 16);

    // S^T partial = K_half · Q_half^T
    f32x16 st = {};
    __builtin_amdgcn_s_setprio(1);
#pragma unroll
    for (int c = 0; c < 16; ++c) {
      const int j = whalf * 32 + 2 * c + hi;
      const int pos = j ^ l31;
      bf16x8 kf = *(const bf16x8*)&K_lds[cur][l31 * 512 + pos * 8];
      st = mfma32(kf, qf[c], st);
    }
    __builtin_amdgcn_s_setprio(0);

    // V quarter B (blks 2,3)
#pragma unroll
    for (int b2 = 0; b2 < 2; ++b2)
#pragma unroll
      for (int c = 0; c < 2; ++c)
        vB[b2 * 2 + c] = *(const bf16x8*)(Vt0 + (size_t)((2 + b2) * 32) * 2048 + c * 16);

    // stage K for step+1 into other buffer (stays in flight across softmax/PV)
    if (step < 63) {
#pragma unroll
      for (int s = 0; s < 8; ++s) {
        const int chunk = s * 256 + tid;
        const int row = chunk >> 6, c = chunk & 63;
        const int cs = c ^ (row & 31);
        gload16(Kb + (size_t)(t0 + 32 + row) * 512 + cs * 8, &K_lds[cur ^ 1][chunk * 8]);
      }
    }

    // pair exchange of partial S^T in f32 (raw barrier, LDS-only wait)
    {
      float* sp = &Sxf[w][l31][0];
#pragma unroll
      for (int g = 0; g < 4; ++g) {
        const int slot = (2 * g + hi) ^ (l31 & 7);
        f32x4 v = {st[4 * g + 0], st[4 * g + 1], st[4 * g + 2], st[4 * g + 3]};
        *(f32x4*)&sp[slot * 4] = v;
      }
    }
    asm volatile("s_waitcnt lgkmcnt(0)" ::: "memory");
    __builtin_amdgcn_s_barrier();
    __builtin_amdgcn_sched_barrier(0);
    float s[16];
    {
      const float* sp = &Sxf[w ^ 1][l31][0];
#pragma unroll
      for (int g = 0; g < 4; ++g) {
        const int slot = (2 * g + hi) ^ (l31 & 7);
        const f32x4 v = *(const f32x4*)&sp[slot * 4];
#pragma unroll
        for (int j = 0; j < 4; ++j) s[4 * g + j] = st[4 * g + j] + v[j];
      }
    }

    // online softmax: lane owns one q (l31), 16 of 32 kv
    float mx = s[0];
#pragma unroll
    for (int r = 1; r < 16; ++r) mx = fmaxf(mx, s[r]);
    mx = fmaxf(mx, __shfl_xor(mx, 32, 64));
    const float mnew = fmaxf(m, mx);
    if (__any(mnew > m)) {
      const float al = __expf(m - mnew);
#pragma unroll
      for (int i = 0; i < 8; ++i) acc[i] *= al;
      lsum *= al;
      m = mnew;
    }
    float p[16];
#pragma unroll
    for (int r = 0; r < 16; ++r) {
      p[r] = __expf(s[r] - m);
      lsum += p[r];
    }

    // V quarter C (blks 4,5)
#pragma unroll
    for (int b2 = 0; b2 < 2; ++b2)
#pragma unroll
      for (int c = 0; c < 2; ++c)
        vC[b2 * 2 + c] = *(const bf16x8*)(Vt0 + (size_t)((4 + b2) * 32) * 2048 + c * 16);

    // P -> B-fragments (T12: cvt_pk + permlane32_swap)
    bf16x8 pf[2];
    {
      u32 wd[8];
#pragma unroll
      for (int g = 0; g < 4; ++g) {
        wd[2 * g] = cvtpk(p[4 * g + 0], p[4 * g + 1]);
        wd[2 * g + 1] = cvtpk(p[4 * g + 2], p[4 * g + 3]);
      }
      pl32swap(wd[0], wd[2]); pl32swap(wd[1], wd[3]);
      pl32swap(wd[4], wd[6]); pl32swap(wd[5], wd[7]);
      u32x4 f0 = {wd[0], wd[1], wd[2], wd[3]};
      u32x4 f1 = {wd[4], wd[5], wd[6], wd[7]};
      pf[0] = __builtin_bit_cast(bf16x8, f0);
      pf[1] = __builtin_bit_cast(bf16x8, f1);
    }

    // V quarter D (blks 6,7)
#pragma unroll
    for (int b2 = 0; b2 < 2; ++b2)
#pragma unroll
      for (int c = 0; c < 2; ++c)
        vD[b2 * 2 + c] = *(const bf16x8*)(Vt0 + (size_t)((6 + b2) * 32) * 2048 + c * 16);

    // O^T += V^T · P (quarters; compiler inserts counted vmcnt before first use)
    __builtin_amdgcn_s_setprio(1);
#pragma unroll
    for (int i = 0; i < 4; ++i) acc[0 + (i >> 1)] = mfma32(vA[i], pf[i & 1], acc[0 + (i >> 1)]);
#pragma unroll
    for (int i = 0; i < 4; ++i) acc[2 + (i >> 1)] = mfma32(vB[i], pf[i & 1], acc[2 + (i >> 1)]);
#pragma unroll
    for (int i = 0; i < 4; ++i) acc[4 + (i >> 1)] = mfma32(vC[i], pf[i & 1], acc[4 + (i >> 1)]);
#pragma unroll
    for (int i = 0; i < 4; ++i) acc[6 + (i >> 1)] = mfma32(vD[i], pf[i & 1], acc[6 + (i >> 1)]);
    __builtin_amdgcn_s_setprio(0);

    // end of step: K stage must be in LDS before next QK^T (vmcnt only, raw barrier)
    asm volatile("s_waitcnt vmcnt(0)" ::: "memory");
    __builtin_amdgcn_s_barrier();
    __builtin_amdgcn_sched_barrier(0);
  }

  // finalize
  lsum += __shfl_xor(lsum, 32, 64);
  const float inv = 1.0f / lsum;
  const int bb = bh >> 3, h = bh & 7;
  const int t = qt * 64 + pr * 32 + l31;
  u16* orow_p = Og + (size_t)(bb * 2048 + t) * 4096 + h * 512;
#pragma unroll
  for (int blk = 0; blk < 8; ++blk) {
    const int dbase = whalf * 256 + blk * 32 + 4 * hi;
#pragma unroll
    for (int g = 0; g < 4; ++g) {
      u16x4 pk;
#pragma unroll
      for (int i = 0; i < 4; ++i) pk[i] = f2bf(acc[blk][4 * g + i] * inv);
      *(u16x4*)(orow_p + dbase + 8 * g) = pk;
    }
  }
}

// ---------------- launcher ----------------

extern "C" void kernel_launch(void* const* d_in, const int* in_sizes, int n_in,
                              void* d_out, int out_size, void* d_ws, size_t ws_size,
                              hipStream_t stream) {
  const float* x = (const float*)d_in[0];
  const float* Wq = (const float*)d_in[1];
  const float* Wk = (const float*)d_in[2];
  const float* Wv = (const float*)d_in[3];
  const float* Wo = (const float*)d_in[4];
  const float* bo = (const float*)d_in[5];
  float* out = (float*)d_out;

  const size_t MB = 1ull << 20;
  int BB;
  if (ws_size >= 280 * MB) BB = 4;
  else if (ws_size >= 152 * MB) BB = 2;
  else BB = 1;

  char* ws = (char*)d_ws;
  u16* xb  = (u16*)(ws);
  u16* Wqp = (u16*)(ws + 8 * MB);
  u16* Wkp = (u16*)(ws + 12 * MB);
  u16* Wvp = (u16*)(ws + 16 * MB);
  u16* Wot = (u16*)(ws + 20 * MB);
  u16* Qg  = (u16*)(ws + 24 * MB);
  u16* Kg  = (u16*)(ws + (24 + 16 * BB) * MB);
  u16* Vtg = (u16*)(ws + (24 + 32 * BB) * MB);
  u16* Og  = (u16*)(ws + (24 + 48 * BB) * MB);

  pack_x_kernel<<<dim3(4096), dim3(256), 0, stream>>>(x, xb);
  pack_wqkv_t<<<dim3(64, 8), dim3(256), 0, stream>>>(Wq, Wqp);
  pack_wqkv_t<<<dim3(64, 8), dim3(256), 0, stream>>>(Wk, Wkp);
  pack_wqkv_t<<<dim3(64, 8), dim3(256), 0, stream>>>(Wv, Wvp);
  pack_wo_t<<<dim3(64, 8), dim3(256), 0, stream>>>(Wo, Wot);

  const float qk_scale = 0.21022410381342865f;  // 1 / 512^0.25

  const int nchunk = 4 / BB;
  for (int c = 0; c < nchunk; ++c) {
    const u16* Ax = xb + (size_t)c * BB * 2048 * 512;
    gemm_bf16<0><<<dim3(32, BB * 16), dim3(256), 0, stream>>>(Ax, Wqp, (void*)Qg, nullptr, 512, qk_scale);
    gemm_bf16<0><<<dim3(32, BB * 16), dim3(256), 0, stream>>>(Ax, Wkp, (void*)Kg, nullptr, 512, qk_scale);
    gemm_bf16<1><<<dim3(32, BB * 16), dim3(256), 0, stream>>>(Ax, Wvp, (void*)Vtg, nullptr, 512, 1.0f);

    attn_kernel<<<dim3(32 * BB * 8), dim3(256), 0, stream>>>(Qg, Kg, Vtg, Og, BB);

    gemm_bf16<2><<<dim3(4, BB * 16), dim3(256), 0, stream>>>(
        Og, Wot, (void*)(out + (size_t)c * BB * 2048 * 512), bo, 4096, 1.0f);
  }
}

// Round 6
// 751.249 us; speedup vs baseline: 2.6499x; 2.6499x over previous
//
#include <hip/hip_runtime.h>

typedef unsigned short u16;
typedef unsigned int u32;
typedef __attribute__((ext_vector_type(8))) short bf16x8;
typedef __attribute__((ext_vector_type(4))) float f32x4;
typedef __attribute__((ext_vector_type(16))) float f32x16;
typedef __attribute__((ext_vector_type(4))) u16 u16x4;
typedef __attribute__((ext_vector_type(4))) u32 u32x4;

__device__ __forceinline__ u16 f2bf(float f) {
  u32 u = __builtin_bit_cast(u32, f);
  return (u16)((u + 0x7FFFu + ((u >> 16) & 1u)) >> 16);
}

__device__ __forceinline__ f32x4 mfma16(bf16x8 a, bf16x8 b, f32x4 c) {
  return __builtin_amdgcn_mfma_f32_16x16x32_bf16(a, b, c, 0, 0, 0);
}
__device__ __forceinline__ f32x16 mfma32(bf16x8 a, bf16x8 b, f32x16 c) {
  return __builtin_amdgcn_mfma_f32_32x32x16_bf16(a, b, c, 0, 0, 0);
}

__device__ __forceinline__ void gload16(const void* g, void* l) {
  __builtin_amdgcn_global_load_lds(
      (const __attribute__((address_space(1))) unsigned int*)g,
      (__attribute__((address_space(3))) unsigned int*)l, 16, 0, 0);
}

__device__ __forceinline__ u32 cvtpk(float lo, float hi) {
  u32 r;
  asm volatile("v_cvt_pk_bf16_f32 %0, %1, %2" : "=v"(r) : "v"(lo), "v"(hi));
  return r;
}
__device__ __forceinline__ void pl32swap(u32& a, u32& b) {
  asm volatile("v_permlane32_swap_b32 %0, %1" : "+v"(a), "+v"(b));
}

// ---------------- pack kernels ----------------

__global__ void pack_x_kernel(const float* __restrict__ x, u16* __restrict__ xb) {
  const int i = blockIdx.x * 256 + threadIdx.x;
  const float4 v = ((const float4*)x)[i];
  u16x4 o;
  o[0] = f2bf(v.x); o[1] = f2bf(v.y); o[2] = f2bf(v.z); o[3] = f2bf(v.w);
  ((u16x4*)xb)[i] = o;
}

// W: [512][4096] col = k*8+h  ->  Wp: [h*512+k][dd]  (tiled LDS transpose)
__global__ void pack_wqkv_t(const float* __restrict__ W, u16* __restrict__ Wp) {
  __shared__ u16 tile[64][72];
  const int t = threadIdx.x;
  const int c0 = blockIdx.x * 64, dd0 = blockIdx.y * 64;
#pragma unroll
  for (int s = 0; s < 4; ++s) {
    const int r = s * 16 + (t >> 4);
    const int q = (t & 15) * 4;
    const float4 v = *(const float4*)&W[(size_t)(dd0 + r) * 4096 + c0 + q];
    tile[r][q + 0] = f2bf(v.x); tile[r][q + 1] = f2bf(v.y);
    tile[r][q + 2] = f2bf(v.z); tile[r][q + 3] = f2bf(v.w);
  }
  __syncthreads();
#pragma unroll
  for (int s = 0; s < 4; ++s) {
    const int cl = s * 16 + (t >> 4);
    const int u = t & 15;
    const int cg = c0 + cl;
    const int orow = (cg & 7) * 512 + (cg >> 3);
    u16x4 o;
#pragma unroll
    for (int i = 0; i < 4; ++i) o[i] = tile[u * 4 + i][cl];
    *(u16x4*)&Wp[(size_t)orow * 512 + dd0 + u * 4] = o;
  }
}

// Wo: [4096][512] -> Wot: [n=512][k=4096]
__global__ void pack_wo_t(const float* __restrict__ W, u16* __restrict__ Wp) {
  __shared__ u16 tile[64][72];
  const int t = threadIdx.x;
  const int k0 = blockIdx.x * 64, n0 = blockIdx.y * 64;
#pragma unroll
  for (int s = 0; s < 4; ++s) {
    const int r = s * 16 + (t >> 4);
    const int q = (t & 15) * 4;
    const float4 v = *(const float4*)&W[(size_t)(k0 + r) * 512 + n0 + q];
    tile[r][q + 0] = f2bf(v.x); tile[r][q + 1] = f2bf(v.y);
    tile[r][q + 2] = f2bf(v.z); tile[r][q + 3] = f2bf(v.w);
  }
  __syncthreads();
#pragma unroll
  for (int s = 0; s < 4; ++s) {
    const int cl = s * 16 + (t >> 4);
    const int u = t & 15;
    u16x4 o;
#pragma unroll
    for (int i = 0; i < 4; ++i) o[i] = tile[u * 4 + i][cl];
    *(u16x4*)&Wp[(size_t)(n0 + cl) * 4096 + k0 + u * 4] = o;
  }
}

// ---------------- GEMM: C[M][N] = A[M][Kd] * B[N][Kd]^T ----------------

template <int MODE>
__global__ __launch_bounds__(256, 2) void gemm_bf16(
    const u16* __restrict__ A, const u16* __restrict__ B,
    void* __restrict__ Cout, const float* __restrict__ bias,
    int Kd, float scale) {
  __shared__ u16 Al[128 * 64];
  __shared__ u16 Bl[128 * 64];
  const int tid = threadIdx.x;
  const int lane = tid & 63;
  const int w = tid >> 6, wm = w >> 1, wn = w & 1;
  const int l15 = lane & 15, lg = lane >> 4;
  const int m0 = blockIdx.y * 128, n0 = blockIdx.x * 128;

  f32x4 acc[4][4];
  const f32x4 zero = {0.f, 0.f, 0.f, 0.f};
#pragma unroll
  for (int i = 0; i < 4; ++i)
#pragma unroll
    for (int j = 0; j < 4; ++j) acc[i][j] = zero;

  const int nk = Kd >> 6;
  for (int kt = 0; kt < nk; ++kt) {
    __syncthreads();
    const int k0 = kt << 6;
#pragma unroll
    for (int s = 0; s < 4; ++s) {
      const int chunk = s * 256 + tid;
      const int row = chunk >> 3, c = chunk & 7;
      const int cs = c ^ (row & 7);
      gload16(A + (size_t)(m0 + row) * Kd + k0 + cs * 8, &Al[chunk * 8]);
    }
#pragma unroll
    for (int s = 0; s < 4; ++s) {
      const int chunk = s * 256 + tid;
      const int row = chunk >> 3, c = chunk & 7;
      const int cs = c ^ (row & 7);
      gload16(B + (size_t)(n0 + row) * Kd + k0 + cs * 8, &Bl[chunk * 8]);
    }
    __syncthreads();
#pragma unroll
    for (int kk = 0; kk < 2; ++kk) {
      bf16x8 af[4], bfr[4];
      const int ch = kk * 4 + lg;
#pragma unroll
      for (int i = 0; i < 4; ++i) {
        const int ar = wm * 64 + i * 16 + l15;
        af[i] = *(const bf16x8*)&Al[ar * 64 + ((ch ^ (ar & 7)) * 8)];
        const int br = wn * 64 + i * 16 + l15;
        bfr[i] = *(const bf16x8*)&Bl[br * 64 + ((ch ^ (br & 7)) * 8)];
      }
#pragma unroll
      for (int i = 0; i < 4; ++i)
#pragma unroll
        for (int j = 0; j < 4; ++j)
          acc[i][j] = mfma16(af[i], bfr[j], acc[i][j]);
    }
  }

#pragma unroll
  for (int i = 0; i < 4; ++i) {
    const int gr0 = m0 + wm * 64 + i * 16 + lg * 4;
#pragma unroll
    for (int j = 0; j < 4; ++j) {
      const int gc = n0 + wn * 64 + j * 16 + l15;
      if constexpr (MODE == 0) {
        u16* O = (u16*)Cout;
        const int h = gc >> 9, d = gc & 511;
#pragma unroll
        for (int r = 0; r < 4; ++r) {
          const int grr = gr0 + r;
          const int bb = grr >> 11, t = grr & 2047;
          O[((size_t)((bb * 8 + h) * 2048 + t) << 9) + d] = f2bf(acc[i][j][r] * scale);
        }
      } else if constexpr (MODE == 1) {
        u16* O = (u16*)Cout;
        const int h = gc >> 9, d = gc & 511;
        const int bb = gr0 >> 11, t = gr0 & 2047;
        u16x4 pk;
#pragma unroll
        for (int r = 0; r < 4; ++r) pk[r] = f2bf(acc[i][j][r]);
        *(u16x4*)&O[((size_t)((bb * 8 + h) * 512 + d) << 11) + t] = pk;
      } else {
        float* O = (float*)Cout;
        const float bv = bias[gc];
#pragma unroll
        for (int r = 0; r < 4; ++r)
          O[(size_t)(gr0 + r) * 512 + gc] = acc[i][j][r] + bv;
      }
    }
  }
}

// ---------------- flash attention v6: 8-wave block, K+V LDS double-buffer ----------------
// Q,K: [bh][2048][512]; Vt: [bh][512][2048]; Og: [bb*2048+t][h*512+d]
// block = 8 waves (512 thr) = 4 pairs; pair owns 32 q rows (128 q/block);
// wave k/d-half = 256. KV block 32, 64 steps.
// LDS = 2x32K (K dbuf) + 2x32K (Vt dbuf) + 32K (Sxf f32) = 163840 B -> 1 block/CU,
// 8 waves = 2 waves/SIMD. Staging for t+1 issued at step START via global_load_lds
// (L2-convoy-friendly, per round-4/5 evidence); single vmcnt(0) drain at step END
// after ~full step of compute -> near-free. 2 barriers/step.

__global__ __launch_bounds__(512, 2) void attn_kernel(
    const u16* __restrict__ Qg, const u16* __restrict__ Kg,
    const u16* __restrict__ Vtg, u16* __restrict__ Og, int nbh_pxcd) {
  __shared__ u16 K_lds[2][32 * 512];   // [buf][kv][k]  chunk swz: c ^ (kv&31)
  __shared__ u16 Vt_lds[2][512 * 32];  // [buf][d][kv]  chunk swz: c ^ ((d>>1)&3)
  __shared__ float Sxf[8][32][32];     // per-wave partial S^T, f32, slot-swizzled

  const int tid = threadIdx.x;
  const int lane = tid & 63;
  const int w = tid >> 6;               // 0..7
  const int pr = w >> 1, whalf = w & 1; // pair 0..3, half 0..1
  const int l31 = lane & 31, hi = lane >> 5;

  // XCD-aware decode: 8 XCDs get contiguous bh chunks
  const int bid = blockIdx.x;
  const int x8 = bid & 7, rest = bid >> 3;
  const int qt = rest & 15;                     // 16 q-tiles of 128 rows
  const int bh = x8 * nbh_pxcd + (rest >> 4);

  const size_t bh_off = (size_t)bh * 2048 * 512;
  const u16* Qb = Qg + bh_off;
  const u16* Kb = Kg + bh_off;
  const u16* Vb = Vtg + bh_off;

  // Q as B-fragments: lane holds Q[q = l31][k = whalf*256 + c*16 + hi*8 + j]
  const int qrow = qt * 128 + pr * 32 + l31;
  bf16x8 qf[16];
  {
    const u16* qp = Qb + (size_t)qrow * 512 + whalf * 256 + hi * 8;
#pragma unroll
    for (int c = 0; c < 16; ++c) qf[c] = *(const bf16x8*)(qp + c * 16);
  }

  f32x16 acc[8];
#pragma unroll
  for (int i = 0; i < 8; ++i) acc[i] = {};
  float m = -1e30f, lsum = 0.f;

  // prologue: stage tiles(0) into buf 0
#pragma unroll
  for (int s = 0; s < 4; ++s) {  // K 32x512: 2048 chunks
    const int chunk = s * 512 + tid;
    const int row = chunk >> 6, c = chunk & 63;
    const int cs = c ^ (row & 31);
    gload16(Kb + (size_t)row * 512 + cs * 8, &K_lds[0][chunk * 8]);
  }
#pragma unroll
  for (int s = 0; s < 4; ++s) {  // Vt 512x32: 2048 chunks
    const int chunk = s * 512 + tid;
    const int row = chunk >> 2, c = chunk & 3;
    const int cs = c ^ ((row >> 1) & 3);
    gload16(Vb + (size_t)row * 2048 + cs * 8, &Vt_lds[0][chunk * 8]);
  }
  asm volatile("s_waitcnt vmcnt(0)" ::: "memory");
  __builtin_amdgcn_s_barrier();
  __builtin_amdgcn_sched_barrier(0);

  for (int step = 0; step < 64; ++step) {
    const int cur = step & 1;
    const int t0 = step * 32;

    // phase 1: issue staging of tiles(t+1) into buf cur^1 (in flight all step)
    if (step < 63) {
#pragma unroll
      for (int s = 0; s < 4; ++s) {
        const int chunk = s * 512 + tid;
        const int row = chunk >> 6, c = chunk & 63;
        const int cs = c ^ (row & 31);
        gload16(Kb + (size_t)(t0 + 32 + row) * 512 + cs * 8, &K_lds[cur ^ 1][chunk * 8]);
      }
#pragma unroll
      for (int s = 0; s < 4; ++s) {
        const int chunk = s * 512 + tid;
        const int row = chunk >> 2, c = chunk & 3;
        const int cs = c ^ ((row >> 1) & 3);
        gload16(Vb + (size_t)row * 2048 + t0 + 32 + cs * 8, &Vt_lds[cur ^ 1][chunk * 8]);
      }
    }

    // phase 2: S^T partial = K_half · Q_half^T : rows=kv, cols=q
    f32x16 st = {};
    __builtin_amdgcn_s_setprio(1);
#pragma unroll
    for (int c = 0; c < 16; ++c) {
      const int j = whalf * 32 + 2 * c + hi;
      const int pos = j ^ l31;
      bf16x8 kf = *(const bf16x8*)&K_lds[cur][l31 * 512 + pos * 8];
      st = mfma32(kf, qf[c], st);
    }
    __builtin_amdgcn_s_setprio(0);

    // phase 3: pair exchange of partial S^T in f32 (LDS-only wait at barrier)
    {
      float* sp = &Sxf[w][l31][0];
#pragma unroll
      for (int g = 0; g < 4; ++g) {
        const int slot = (2 * g + hi) ^ (l31 & 7);
        f32x4 v = {st[4 * g + 0], st[4 * g + 1], st[4 * g + 2], st[4 * g + 3]};
        *(f32x4*)&sp[slot * 4] = v;
      }
    }
    asm volatile("s_waitcnt lgkmcnt(0)" ::: "memory");
    __builtin_amdgcn_s_barrier();
    __builtin_amdgcn_sched_barrier(0);
    float s[16];
    {
      const float* sp = &Sxf[w ^ 1][l31][0];
#pragma unroll
      for (int g = 0; g < 4; ++g) {
        const int slot = (2 * g + hi) ^ (l31 & 7);
        const f32x4 v = *(const f32x4*)&sp[slot * 4];
#pragma unroll
        for (int j = 0; j < 4; ++j) s[4 * g + j] = st[4 * g + j] + v[j];
      }
    }

    // phase 4: online softmax (lane owns q = l31; 16 of 32 kv)
    float mx = s[0];
#pragma unroll
    for (int r = 1; r < 16; ++r) mx = fmaxf(mx, s[r]);
    mx = fmaxf(mx, __shfl_xor(mx, 32, 64));
    const float mnew = fmaxf(m, mx);
    if (__any(mnew > m)) {
      const float al = __expf(m - mnew);
#pragma unroll
      for (int i = 0; i < 8; ++i) acc[i] *= al;
      lsum *= al;
      m = mnew;
    }
    float p[16];
#pragma unroll
    for (int r = 0; r < 16; ++r) {
      p[r] = __expf(s[r] - m);
      lsum += p[r];
    }

    // phase 5: P -> B-fragments (T12: cvt_pk + permlane32_swap)
    bf16x8 pf[2];
    {
      u32 wd[8];
#pragma unroll
      for (int g = 0; g < 4; ++g) {
        wd[2 * g] = cvtpk(p[4 * g + 0], p[4 * g + 1]);
        wd[2 * g + 1] = cvtpk(p[4 * g + 2], p[4 * g + 3]);
      }
      pl32swap(wd[0], wd[2]); pl32swap(wd[1], wd[3]);
      pl32swap(wd[4], wd[6]); pl32swap(wd[5], wd[7]);
      u32x4 f0 = {wd[0], wd[1], wd[2], wd[3]};
      u32x4 f1 = {wd[4], wd[5], wd[6], wd[7]};
      pf[0] = __builtin_bit_cast(bf16x8, f0);
      pf[1] = __builtin_bit_cast(bf16x8, f1);
    }

    // phase 6: O^T += V^T · P : rows=d (wave's 256-half), cols=q
    __builtin_amdgcn_s_setprio(1);
#pragma unroll
    for (int blk = 0; blk < 8; ++blk) {
      const int drow = whalf * 256 + blk * 32 + l31;
#pragma unroll
      for (int c = 0; c < 2; ++c) {
        const int pos = (2 * c + hi) ^ ((drow >> 1) & 3);
        bf16x8 vf = *(const bf16x8*)&Vt_lds[cur][drow * 32 + pos * 8];
        acc[blk] = mfma32(vf, pf[c], acc[blk]);
      }
    }
    __builtin_amdgcn_s_setprio(0);

    // phase 7: staging of t+1 must be complete & visible before next step
    asm volatile("s_waitcnt vmcnt(0)" ::: "memory");
    __builtin_amdgcn_s_barrier();
    __builtin_amdgcn_sched_barrier(0);
  }

  // finalize
  lsum += __shfl_xor(lsum, 32, 64);
  const float inv = 1.0f / lsum;
  const int bb = bh >> 3, h = bh & 7;
  const int t = qt * 128 + pr * 32 + l31;
  u16* orow_p = Og + (size_t)(bb * 2048 + t) * 4096 + h * 512;
#pragma unroll
  for (int blk = 0; blk < 8; ++blk) {
    const int dbase = whalf * 256 + blk * 32 + 4 * hi;
#pragma unroll
    for (int g = 0; g < 4; ++g) {
      u16x4 pk;
#pragma unroll
      for (int i = 0; i < 4; ++i) pk[i] = f2bf(acc[blk][4 * g + i] * inv);
      *(u16x4*)(orow_p + dbase + 8 * g) = pk;
    }
  }
}

// ---------------- launcher ----------------

extern "C" void kernel_launch(void* const* d_in, const int* in_sizes, int n_in,
                              void* d_out, int out_size, void* d_ws, size_t ws_size,
                              hipStream_t stream) {
  const float* x = (const float*)d_in[0];
  const float* Wq = (const float*)d_in[1];
  const float* Wk = (const float*)d_in[2];
  const float* Wv = (const float*)d_in[3];
  const float* Wo = (const float*)d_in[4];
  const float* bo = (const float*)d_in[5];
  float* out = (float*)d_out;

  const size_t MB = 1ull << 20;
  int BB;
  if (ws_size >= 280 * MB) BB = 4;
  else if (ws_size >= 152 * MB) BB = 2;
  else BB = 1;

  char* ws = (char*)d_ws;
  u16* xb  = (u16*)(ws);
  u16* Wqp = (u16*)(ws + 8 * MB);
  u16* Wkp = (u16*)(ws + 12 * MB);
  u16* Wvp = (u16*)(ws + 16 * MB);
  u16* Wot = (u16*)(ws + 20 * MB);
  u16* Qg  = (u16*)(ws + 24 * MB);
  u16* Kg  = (u16*)(ws + (24 + 16 * BB) * MB);
  u16* Vtg = (u16*)(ws + (24 + 32 * BB) * MB);
  u16* Og  = (u16*)(ws + (24 + 48 * BB) * MB);

  pack_x_kernel<<<dim3(4096), dim3(256), 0, stream>>>(x, xb);
  pack_wqkv_t<<<dim3(64, 8), dim3(256), 0, stream>>>(Wq, Wqp);
  pack_wqkv_t<<<dim3(64, 8), dim3(256), 0, stream>>>(Wk, Wkp);
  pack_wqkv_t<<<dim3(64, 8), dim3(256), 0, stream>>>(Wv, Wvp);
  pack_wo_t<<<dim3(64, 8), dim3(256), 0, stream>>>(Wo, Wot);

  const float qk_scale = 0.21022410381342865f;  // 1 / 512^0.25

  const int nchunk = 4 / BB;
  for (int c = 0; c < nchunk; ++c) {
    const u16* Ax = xb + (size_t)c * BB * 2048 * 512;
    gemm_bf16<0><<<dim3(32, BB * 16), dim3(256), 0, stream>>>(Ax, Wqp, (void*)Qg, nullptr, 512, qk_scale);
    gemm_bf16<0><<<dim3(32, BB * 16), dim3(256), 0, stream>>>(Ax, Wkp, (void*)Kg, nullptr, 512, qk_scale);
    gemm_bf16<1><<<dim3(32, BB * 16), dim3(256), 0, stream>>>(Ax, Wvp, (void*)Vtg, nullptr, 512, 1.0f);

    attn_kernel<<<dim3(16 * BB * 8), dim3(512), 0, stream>>>(Qg, Kg, Vtg, Og, BB);

    gemm_bf16<2><<<dim3(4, BB * 16), dim3(256), 0, stream>>>(
        Og, Wot, (void*)(out + (size_t)c * BB * 2048 * 512), bo, 4096, 1.0f);
  }
}